// Round 2
// baseline (73.608 us; speedup 1.0000x reference)
//
#include <hip/hip_runtime.h>
#include <math.h>

#define N_TOK 8192
#define DIM   4096
#define NEXP  8
#define TPW   4                 // tokens per wave
#define HALF  (DIM / 2)         // each wave covers half of D
#define ITERS (HALF / 256)      // 8 iterations of 256 floats (lane*4)

// Block = 256 threads = 4 waves, handles 8 tokens:
//   wave 0: tokens [n0..n0+3], d in [0,2048)      (group 0, half 0)
//   wave 1: tokens [n0..n0+3], d in [2048,4096)   (group 0, half 1)
//   wave 2: tokens [n0+4..n0+7], d in [0,2048)    (group 1, half 0)
//   wave 3: tokens [n0+4..n0+7], d in [2048,4096) (group 1, half 1)
// Half-1 partials cross over via 256 B of LDS; half-0 waves do the epilogue.
__global__ __launch_bounds__(256, 4) void router_kernel(
    const float* __restrict__ x,   // [N_TOK, DIM]
    const float* __restrict__ w,   // [NEXP, DIM]
    float* __restrict__ out)       // [N_TOK*8] combine ++ [N_TOK*2] idx-as-float
{
    __shared__ float red[2][TPW][NEXP];

    const int lane   = threadIdx.x & 63;
    const int waveid = threadIdx.x >> 6;   // 0..3
    const int g      = waveid >> 1;        // token group within block
    const int h      = waveid & 1;         // d-half
    const int n0     = blockIdx.x * 8 + g * TPW;

    float acc[TPW][NEXP];
    #pragma unroll
    for (int t = 0; t < TPW; ++t)
        #pragma unroll
        for (int e = 0; e < NEXP; ++e) acc[t][e] = 0.0f;

    const int dbase = h * HALF + lane * 4;
    const float* xr[TPW];
    #pragma unroll
    for (int t = 0; t < TPW; ++t)
        xr[t] = x + (size_t)(n0 + t) * DIM + dbase;
    const float* wr = w + dbase;

    // prefetch first x slice
    float4 xv[TPW], xn[TPW];
    #pragma unroll
    for (int t = 0; t < TPW; ++t)
        xv[t] = *(const float4*)(xr[t]);

    #pragma unroll 2
    for (int it = 0; it < ITERS; ++it) {
        const bool more = (it + 1 < ITERS);
        if (more) {
            const int off = (it + 1) * 256;
            #pragma unroll
            for (int t = 0; t < TPW; ++t)
                xn[t] = *(const float4*)(xr[t] + off);
        }

        float4 wv[NEXP];
        #pragma unroll
        for (int e = 0; e < NEXP; ++e)
            wv[e] = *(const float4*)(wr + (size_t)e * DIM + it * 256);

        #pragma unroll
        for (int t = 0; t < TPW; ++t) {
            #pragma unroll
            for (int e = 0; e < NEXP; ++e) {
                acc[t][e] = fmaf(xv[t].x, wv[e].x,
                            fmaf(xv[t].y, wv[e].y,
                            fmaf(xv[t].z, wv[e].z,
                            fmaf(xv[t].w, wv[e].w, acc[t][e]))));
            }
        }

        if (more) {
            #pragma unroll
            for (int t = 0; t < TPW; ++t) xv[t] = xn[t];
        }
    }

    // 64-lane butterfly: every lane ends with the full half-D partial sum
    #pragma unroll
    for (int t = 0; t < TPW; ++t) {
        #pragma unroll
        for (int e = 0; e < NEXP; ++e) {
            float v = acc[t][e];
            #pragma unroll
            for (int off = 32; off >= 1; off >>= 1)
                v += __shfl_xor(v, off, 64);
            acc[t][e] = v;
        }
    }

    // half 1 -> LDS
    if (h == 1 && lane == 0) {
        #pragma unroll
        for (int t = 0; t < TPW; ++t) {
            *(float4*)&red[g][t][0] = make_float4(acc[t][0], acc[t][1], acc[t][2], acc[t][3]);
            *(float4*)&red[g][t][4] = make_float4(acc[t][4], acc[t][5], acc[t][6], acc[t][7]);
        }
    }
    __syncthreads();

    if (h == 0) {
        #pragma unroll
        for (int t = 0; t < TPW; ++t) {
            // broadcast reads (all lanes same address -> no conflict)
            float4 r0 = *(const float4*)&red[g][t][0];
            float4 r1 = *(const float4*)&red[g][t][4];
            acc[t][0] += r0.x; acc[t][1] += r0.y; acc[t][2] += r0.z; acc[t][3] += r0.w;
            acc[t][4] += r1.x; acc[t][5] += r1.y; acc[t][6] += r1.z; acc[t][7] += r1.w;
        }

        #pragma unroll
        for (int t = 0; t < TPW; ++t) {
            // argmax: strict >, ascending scan => lowest index wins ties (lax.top_k)
            float m1 = acc[t][0]; int i1 = 0;
            #pragma unroll
            for (int e = 1; e < NEXP; ++e)
                if (acc[t][e] > m1) { m1 = acc[t][e]; i1 = e; }
            float m2 = -INFINITY; int i2 = 0;
            #pragma unroll
            for (int e = 0; e < NEXP; ++e)
                if (e != i1 && acc[t][e] > m2) { m2 = acc[t][e]; i2 = e; }

            // softmax denom cancels under top-k renorm:
            // w1 = 1/(1+exp(l2-l1)), w2 = exp(l2-l1)/(1+exp(l2-l1))
            const float e2  = expf(m2 - m1);
            const float inv = 1.0f / (1.0f + e2);
            const float w1  = inv;
            const float w2  = e2 * inv;

            if (lane == 0) {
                const int n = n0 + t;
                float c[8];
                #pragma unroll
                for (int e = 0; e < 8; ++e)
                    c[e] = (e == i1) ? w1 : ((e == i2) ? w2 : 0.0f);
                float4* cp = (float4*)(out + (size_t)n * 8);
                cp[0] = make_float4(c[0], c[1], c[2], c[3]);
                cp[1] = make_float4(c[4], c[5], c[6], c[7]);
                float* ip = out + (size_t)N_TOK * 8 + (size_t)n * 2;
                ip[0] = (float)i1;
                ip[1] = (float)i2;
            }
        }
    }
}

extern "C" void kernel_launch(void* const* d_in, const int* in_sizes, int n_in,
                              void* d_out, int out_size, void* d_ws, size_t ws_size,
                              hipStream_t stream) {
    const float* x = (const float*)d_in[0];   // [8192, 4096] f32
    const float* w = (const float*)d_in[1];   // [8, 4096] f32
    float* out = (float*)d_out;

    dim3 grid(N_TOK / 8);   // 1024 blocks, 8 tokens each
    dim3 block(256);
    hipLaunchKernelGGL(router_kernel, grid, block, 0, stream, x, w, out);
}

// Round 3
// 38.062 us; speedup vs baseline: 1.9339x; 1.9339x over previous
//
#include <hip/hip_runtime.h>
#include <math.h>

#define N_TOK 8192
#define DIM   4096
#define NEXP  8
#define TPW   4                 // tokens per wave, full D per wave
#define ITERS (DIM / 256)       // 16 iterations of 256 floats (lane*4)

__global__ __launch_bounds__(256) void router_kernel(
    const float* __restrict__ x,   // [N_TOK, DIM]
    const float* __restrict__ w,   // [NEXP, DIM]
    float* __restrict__ out)       // [N_TOK*8] combine ++ [N_TOK*2] idx-as-float
{
    const int lane   = threadIdx.x & 63;
    const int waveid = threadIdx.x >> 6;           // 0..3
    const int group  = blockIdx.x * 4 + waveid;    // global wave id
    const int n0     = group * TPW;

    float acc[TPW][NEXP];
    #pragma unroll
    for (int t = 0; t < TPW; ++t)
        #pragma unroll
        for (int e = 0; e < NEXP; ++e) acc[t][e] = 0.0f;

    const float* xp = x + (size_t)n0 * DIM + lane * 4;  // token t at xp + t*DIM
    const float* wp = w + lane * 4;                     // expert e at wp + e*DIM

    // Double-buffered register pipeline: all 12 loads for iter it+1 are
    // issued BEFORE the FMAs of iter it, so the compiler emits one counted
    // s_waitcnt vmcnt(12) per iteration and keeps 12 KB/wave in flight.
    float4 xv[TPW], xn[TPW], wv[NEXP], wn[NEXP];

    #pragma unroll
    for (int t = 0; t < TPW; ++t)
        xv[t] = *(const float4*)(xp + (size_t)t * DIM);
    #pragma unroll
    for (int e = 0; e < NEXP; ++e)
        wv[e] = *(const float4*)(wp + (size_t)e * DIM);

    #pragma unroll 2
    for (int it = 0; it < ITERS; ++it) {
        const bool more = (it + 1 < ITERS);
        const int  off  = (it + 1) * 256;
        if (more) {
            #pragma unroll
            for (int t = 0; t < TPW; ++t)
                xn[t] = *(const float4*)(xp + (size_t)t * DIM + off);
            #pragma unroll
            for (int e = 0; e < NEXP; ++e)
                wn[e] = *(const float4*)(wp + (size_t)e * DIM + off);
        }

        #pragma unroll
        for (int t = 0; t < TPW; ++t) {
            #pragma unroll
            for (int e = 0; e < NEXP; ++e) {
                acc[t][e] = fmaf(xv[t].x, wv[e].x,
                            fmaf(xv[t].y, wv[e].y,
                            fmaf(xv[t].z, wv[e].z,
                            fmaf(xv[t].w, wv[e].w, acc[t][e]))));
            }
        }

        if (more) {
            #pragma unroll
            for (int t = 0; t < TPW; ++t) xv[t] = xn[t];
            #pragma unroll
            for (int e = 0; e < NEXP; ++e) wv[e] = wn[e];
        }
    }

    // 64-lane butterfly: every lane ends with the full logit
    #pragma unroll
    for (int t = 0; t < TPW; ++t) {
        #pragma unroll
        for (int e = 0; e < NEXP; ++e) {
            float v = acc[t][e];
            #pragma unroll
            for (int off = 32; off >= 1; off >>= 1)
                v += __shfl_xor(v, off, 64);
            acc[t][e] = v;
        }
    }

    // Epilogue: top-2 + renormalized softmax weights (denominator cancels).
    #pragma unroll
    for (int t = 0; t < TPW; ++t) {
        // argmax: strict >, ascending scan => lowest index wins ties (lax.top_k)
        float m1 = acc[t][0]; int i1 = 0;
        #pragma unroll
        for (int e = 1; e < NEXP; ++e)
            if (acc[t][e] > m1) { m1 = acc[t][e]; i1 = e; }
        float m2 = -INFINITY; int i2 = 0;
        #pragma unroll
        for (int e = 0; e < NEXP; ++e)
            if (e != i1 && acc[t][e] > m2) { m2 = acc[t][e]; i2 = e; }

        // w1 = 1/(1+exp(l2-l1)), w2 = exp(l2-l1)/(1+exp(l2-l1))
        const float e2  = expf(m2 - m1);
        const float inv = 1.0f / (1.0f + e2);
        const float w1  = inv;
        const float w2  = e2 * inv;

        if (lane == 0) {
            const int n = n0 + t;
            float c[8];
            #pragma unroll
            for (int e = 0; e < 8; ++e)
                c[e] = (e == i1) ? w1 : ((e == i2) ? w2 : 0.0f);
            float4* cp = (float4*)(out + (size_t)n * 8);
            cp[0] = make_float4(c[0], c[1], c[2], c[3]);
            cp[1] = make_float4(c[4], c[5], c[6], c[7]);
            float* ip = out + (size_t)N_TOK * 8 + (size_t)n * 2;
            ip[0] = (float)i1;
            ip[1] = (float)i2;
        }
    }
}

extern "C" void kernel_launch(void* const* d_in, const int* in_sizes, int n_in,
                              void* d_out, int out_size, void* d_ws, size_t ws_size,
                              hipStream_t stream) {
    const float* x = (const float*)d_in[0];   // [8192, 4096] f32
    const float* w = (const float*)d_in[1];   // [8, 4096] f32
    float* out = (float*)d_out;

    dim3 grid(N_TOK / (4 * TPW));   // 512 blocks x 4 waves x 4 tokens
    dim3 block(256);
    hipLaunchKernelGGL(router_kernel, grid, block, 0, stream, x, w, out);
}

// Round 4
// 32.995 us; speedup vs baseline: 2.2309x; 1.1536x over previous
//
#include <hip/hip_runtime.h>
#include <math.h>

#define N_TOK 8192
#define DIM   4096
#define NEXP  8
#define TPW   4                 // tokens per wave-pair
#define HALF  (DIM / 2)         // each wave covers half of D
#define ITERS (HALF / 256)      // 8 iterations of 256 floats (lane*4)

// Block = 256 threads = 4 waves, 8 tokens per block:
//   wave (g,h): tokens [n0+g*4 .. n0+g*4+3], d-half h.
// Half-1 partials cross to half-0 waves via 256 B LDS; half-0 does epilogue.
// NO launch_bounds register cap (R2's cap caused 145 MB of scratch spills).
__global__ __launch_bounds__(256) void router_kernel(
    const float* __restrict__ x,   // [N_TOK, DIM]
    const float* __restrict__ w,   // [NEXP, DIM]
    float* __restrict__ out)       // [N_TOK*8] combine ++ [N_TOK*2] idx-as-float
{
    __shared__ float red[2][TPW][NEXP];

    const int lane   = threadIdx.x & 63;
    const int waveid = threadIdx.x >> 6;   // 0..3
    const int g      = waveid >> 1;        // token group within block
    const int h      = waveid & 1;         // d-half
    const int n0     = blockIdx.x * 8 + g * TPW;

    float acc[TPW][NEXP];
    #pragma unroll
    for (int t = 0; t < TPW; ++t)
        #pragma unroll
        for (int e = 0; e < NEXP; ++e) acc[t][e] = 0.0f;

    const int dbase = h * HALF + lane * 4;
    const float* xr = x + (size_t)n0 * DIM + dbase;  // token t at xr + t*DIM
    const float* wr = w + dbase;                     // expert e at wr + e*DIM

    // x prefetch: 3-slot rotation, issued 2 iterations ahead.
    float4 xb[3][TPW];
    #pragma unroll
    for (int t = 0; t < TPW; ++t)
        xb[0][t] = *(const float4*)(xr + (size_t)t * DIM);
    #pragma unroll
    for (int t = 0; t < TPW; ++t)
        xb[1][t] = *(const float4*)(xr + (size_t)t * DIM + 256);

    #pragma unroll   // full unroll keeps %3 rotation statically indexed
    for (int it = 0; it < ITERS; ++it) {
        // issue x loads for it+2 FIRST (deep HBM queue)
        if (it + 2 < ITERS) {
            const int off = (it + 2) * 256;
            #pragma unroll
            for (int t = 0; t < TPW; ++t)
                xb[(it + 2) % 3][t] = *(const float4*)(xr + (size_t)t * DIM + off);
        }

        // w slice (L1/L2-resident, single-buffered)
        float4 wv[NEXP];
        #pragma unroll
        for (int e = 0; e < NEXP; ++e)
            wv[e] = *(const float4*)(wr + (size_t)e * DIM + it * 256);

        #pragma unroll
        for (int t = 0; t < TPW; ++t) {
            const float4 xv = xb[it % 3][t];
            #pragma unroll
            for (int e = 0; e < NEXP; ++e) {
                acc[t][e] = fmaf(xv.x, wv[e].x,
                            fmaf(xv.y, wv[e].y,
                            fmaf(xv.z, wv[e].z,
                            fmaf(xv.w, wv[e].w, acc[t][e]))));
            }
        }
    }

    // 64-lane butterfly: every lane ends with the half-D partial sum
    #pragma unroll
    for (int t = 0; t < TPW; ++t) {
        #pragma unroll
        for (int e = 0; e < NEXP; ++e) {
            float v = acc[t][e];
            #pragma unroll
            for (int off = 32; off >= 1; off >>= 1)
                v += __shfl_xor(v, off, 64);
            acc[t][e] = v;
        }
    }

    // half 1 -> LDS
    if (h == 1 && lane == 0) {
        #pragma unroll
        for (int t = 0; t < TPW; ++t) {
            *(float4*)&red[g][t][0] = make_float4(acc[t][0], acc[t][1], acc[t][2], acc[t][3]);
            *(float4*)&red[g][t][4] = make_float4(acc[t][4], acc[t][5], acc[t][6], acc[t][7]);
        }
    }
    __syncthreads();

    if (h == 0) {
        #pragma unroll
        for (int t = 0; t < TPW; ++t) {
            float4 r0 = *(const float4*)&red[g][t][0];   // broadcast reads
            float4 r1 = *(const float4*)&red[g][t][4];
            acc[t][0] += r0.x; acc[t][1] += r0.y; acc[t][2] += r0.z; acc[t][3] += r0.w;
            acc[t][4] += r1.x; acc[t][5] += r1.y; acc[t][6] += r1.z; acc[t][7] += r1.w;
        }

        #pragma unroll
        for (int t = 0; t < TPW; ++t) {
            // argmax: strict >, ascending scan => lowest index wins ties (lax.top_k)
            float m1 = acc[t][0]; int i1 = 0;
            #pragma unroll
            for (int e = 1; e < NEXP; ++e)
                if (acc[t][e] > m1) { m1 = acc[t][e]; i1 = e; }
            float m2 = -INFINITY; int i2 = 0;
            #pragma unroll
            for (int e = 0; e < NEXP; ++e)
                if (e != i1 && acc[t][e] > m2) { m2 = acc[t][e]; i2 = e; }

            // softmax denom cancels under top-2 renorm:
            // w1 = 1/(1+exp(l2-l1)), w2 = exp(l2-l1)/(1+exp(l2-l1))
            const float e2  = expf(m2 - m1);
            const float inv = 1.0f / (1.0f + e2);
            const float w1  = inv;
            const float w2  = e2 * inv;

            if (lane == 0) {
                const int n = n0 + t;
                float c[8];
                #pragma unroll
                for (int e = 0; e < 8; ++e)
                    c[e] = (e == i1) ? w1 : ((e == i2) ? w2 : 0.0f);
                float4* cp = (float4*)(out + (size_t)n * 8);
                cp[0] = make_float4(c[0], c[1], c[2], c[3]);
                cp[1] = make_float4(c[4], c[5], c[6], c[7]);
                float* ip = out + (size_t)N_TOK * 8 + (size_t)n * 2;
                ip[0] = (float)i1;
                ip[1] = (float)i2;
            }
        }
    }
}

extern "C" void kernel_launch(void* const* d_in, const int* in_sizes, int n_in,
                              void* d_out, int out_size, void* d_ws, size_t ws_size,
                              hipStream_t stream) {
    const float* x = (const float*)d_in[0];   // [8192, 4096] f32
    const float* w = (const float*)d_in[1];   // [8, 4096] f32
    float* out = (float*)d_out;

    dim3 grid(N_TOK / 8);   // 1024 blocks x 8 tokens
    dim3 block(256);
    hipLaunchKernelGGL(router_kernel, grid, block, 0, stream, x, w, out);
}